// Round 1
// baseline (516.163 us; speedup 1.0000x reference)
//
#include <hip/hip_runtime.h>
#include <hip/hip_bf16.h>

#define V_ 100000
#define E_ 256
#define H_ 512
#define L_ 50000
#define S_ 512
#define T_ 64
#define NB_ 782        // ceil(L/64)
#define NBP_ 784
#define NWG_ 32

__device__ __forceinline__ float sigm(float x){ return 1.0f/(1.0f+__expf(-x)); }
__device__ __forceinline__ unsigned bf16rne(float x){
    unsigned u = __float_as_uint(x);
    return (u + 0x7fffu + ((u >> 16) & 1u)) >> 16;
}

// ---------------- K1: per-step attention (embed -> q -> softmax -> ctx) ----
__global__ __launch_bounds__(256) void k_attn(
    const float* __restrict__ enc, const float* __restrict__ emb,
    const float* __restrict__ W_attn, const float* __restrict__ b_attn,
    const int* __restrict__ word_inputs, float* __restrict__ ctx_out)
{
    __shared__ float e_l[E_];
    __shared__ float q_l[H_];
    __shared__ float sc[S_];
    __shared__ float red[8];
    const int t = blockIdx.x, tid = threadIdx.x;
    const int widx = word_inputs[t];

    e_l[tid] = emb[(long)widx * E_ + tid];
    __syncthreads();

    // q = W_attn @ e + b_attn  (each thread 2 rows)
    for (int rr = 0; rr < 2; ++rr) {
        int r = tid + rr * 256;
        const float4* wrow = (const float4*)(W_attn + r * E_);
        const float4* ev = (const float4*)e_l;
        float acc = b_attn[r];
        #pragma unroll 8
        for (int j = 0; j < E_ / 4; ++j) {
            float4 w = wrow[j], e4 = ev[j];
            acc += w.x*e4.x + w.y*e4.y + w.z*e4.z + w.w*e4.w;
        }
        q_l[r] = acc;
    }
    __syncthreads();

    // scores[s] = enc[s] . q
    for (int rr = 0; rr < 2; ++rr) {
        int s = tid + rr * 256;
        const float4* er = (const float4*)(enc + s * H_);
        const float4* qv = (const float4*)q_l;
        float acc = 0.f;
        #pragma unroll 8
        for (int j = 0; j < H_ / 4; ++j) {
            float4 a = er[j], b = qv[j];
            acc += a.x*b.x + a.y*b.y + a.z*b.z + a.w*b.w;
        }
        sc[s] = acc;
    }
    __syncthreads();

    // softmax over 512
    float m = fmaxf(sc[tid], sc[tid + 256]);
    for (int off = 32; off; off >>= 1) m = fmaxf(m, __shfl_down(m, off));
    if ((tid & 63) == 0) red[tid >> 6] = m;
    __syncthreads();
    if (tid == 0) red[4] = fmaxf(fmaxf(red[0], red[1]), fmaxf(red[2], red[3]));
    __syncthreads();
    m = red[4];
    float e0 = __expf(sc[tid] - m), e1 = __expf(sc[tid + 256] - m);
    sc[tid] = e0; sc[tid + 256] = e1;
    float ssum = e0 + e1;
    for (int off = 32; off; off >>= 1) ssum += __shfl_down(ssum, off);
    if ((tid & 63) == 0) red[tid >> 6] = ssum;
    __syncthreads();
    if (tid == 0) red[5] = red[0] + red[1] + red[2] + red[3];
    __syncthreads();
    float inv = 1.0f / red[5];

    // ctx[h] = sum_s alpha[s] * enc[s][h]   (coalesced over h)
    for (int rr = 0; rr < 2; ++rr) {
        int h = tid + rr * 256;
        float acc = 0.f;
        #pragma unroll 4
        for (int s = 0; s < S_; ++s) acc += sc[s] * enc[s * H_ + h];
        ctx_out[t * H_ + h] = acc * inv;
    }
}

// ---------------- K2: A[t] = W_ih @ ctx_t + b_ih + b_hh ---------------------
__global__ __launch_bounds__(256) void k_gatepre(
    const float* __restrict__ ctx, const float* __restrict__ W_ih,
    const float* __restrict__ b_ih, const float* __restrict__ b_hh,
    float* __restrict__ A_pre)
{
    __shared__ float ctx_t[H_ * 64];   // transposed [k][t], conflict-free
    __shared__ float w_l[8 * H_];
    const int tid = threadIdx.x;
    const int r0 = blockIdx.x * 8;

    for (int i = 0; i < 32; ++i) {
        int p = tid + i * 256;             // float4 index over [64][512]
        int t = p >> 7, k4 = p & 127;
        float4 v = ((const float4*)ctx)[p];
        ctx_t[(k4*4+0)*64 + t] = v.x;
        ctx_t[(k4*4+1)*64 + t] = v.y;
        ctx_t[(k4*4+2)*64 + t] = v.z;
        ctx_t[(k4*4+3)*64 + t] = v.w;
    }
    for (int i = 0; i < 4; ++i) {
        int p = tid + i * 256;             // float4 index over [8][512]
        int row = p >> 7, k4 = p & 127;
        float4 v = ((const float4*)W_ih)[(r0 + row) * (H_/4) + k4];
        float* dst = &w_l[row * H_ + k4 * 4];
        dst[0]=v.x; dst[1]=v.y; dst[2]=v.z; dst[3]=v.w;
    }
    __syncthreads();

    const int t = tid & 63, half = tid >> 6;
    const float* w0 = &w_l[(half*2+0) * H_];
    const float* w1 = &w_l[(half*2+1) * H_];
    float acc0 = 0.f, acc1 = 0.f;
    #pragma unroll 4
    for (int k = 0; k < H_; ++k) {
        float cv = ctx_t[k * 64 + t];
        acc0 += w0[k] * cv;
        acc1 += w1[k] * cv;
    }
    int ra = r0 + half * 2, rb = ra + 1;
    A_pre[t * 2048 + ra] = acc0 + b_ih[ra] + b_hh[ra];
    A_pre[t * 2048 + rb] = acc1 + b_ih[rb] + b_hh[rb];
}

// ---------------- K3: persistent sequential LSTM (32 WGs, spin-synced) ------
__global__ __launch_bounds__(256) void k_lstm(
    const float* __restrict__ W_hh, const float* __restrict__ A_pre,
    const float* __restrict__ h0, const float* __restrict__ c0,
    float* __restrict__ h_buf, int* __restrict__ slots)
{
    __shared__ float Wl_t[H_ * 64];   // transposed [k][lr]
    __shared__ float h_l[H_];
    __shared__ float red[256];
    __shared__ float g_l[64];
    __shared__ float c_l[16];
    const int tid = threadIdx.x, w = blockIdx.x;
    const int base = w * 16;

    for (int i = 0; i < 32; ++i) {
        int p = tid + i * 256;            // float4 index over [64][512]
        int lr = p >> 7, k4 = p & 127;
        int R = ((lr >> 4) << 9) + base + (lr & 15);
        float4 v = ((const float4*)W_hh)[R * (H_/4) + k4];
        Wl_t[(k4*4+0)*64 + lr] = v.x;
        Wl_t[(k4*4+1)*64 + lr] = v.y;
        Wl_t[(k4*4+2)*64 + lr] = v.z;
        Wl_t[(k4*4+3)*64 + lr] = v.w;
    }
    if (tid < 16) c_l[tid] = c0[base + tid];
    __syncthreads();

    const int lr = tid & 63, seg = tid >> 6;
    const float* wp = &Wl_t[seg * 128 * 64 + lr];
    const float* hp = &h_l[seg * 128];

    for (int t = 0; t < T_; ++t) {
        if (t == 0) {
            h_l[tid]       = h0[tid];
            h_l[tid + 256] = h0[tid + 256];
        } else {
            if (tid < 64) {
                int sl = tid & 31;
                while (true) {
                    int v = __hip_atomic_load(&slots[sl], __ATOMIC_ACQUIRE,
                                              __HIP_MEMORY_SCOPE_AGENT);
                    if (__all(v >= t)) break;
                    __builtin_amdgcn_s_sleep(2);
                }
            }
            __syncthreads();
            h_l[tid]       = __hip_atomic_load(&h_buf[(t-1)*H_ + tid],
                                __ATOMIC_RELAXED, __HIP_MEMORY_SCOPE_AGENT);
            h_l[tid + 256] = __hip_atomic_load(&h_buf[(t-1)*H_ + tid + 256],
                                __ATOMIC_RELAXED, __HIP_MEMORY_SCOPE_AGENT);
        }
        __syncthreads();

        float acc = 0.f;
        #pragma unroll 8
        for (int j = 0; j < 128; ++j) acc += wp[j * 64] * hp[j];
        red[tid] = acc;
        __syncthreads();

        if (tid < 64) {
            int gate = tid >> 4, hi = tid & 15;
            int R = gate * H_ + base + hi;
            g_l[tid] = red[tid] + red[tid+64] + red[tid+128] + red[tid+192]
                     + A_pre[t * 2048 + R];
        }
        __syncthreads();

        if (tid < 16) {
            float gi = sigm(g_l[tid]);
            float gf = sigm(g_l[16 + tid]);
            float gg = tanhf(g_l[32 + tid]);
            float go = sigm(g_l[48 + tid]);
            float c2 = gf * c_l[tid] + gi * gg;
            c_l[tid] = c2;
            float h2 = go * tanhf(c2);
            __hip_atomic_store(&h_buf[t * H_ + base + tid], h2,
                               __ATOMIC_RELAXED, __HIP_MEMORY_SCOPE_AGENT);
        }
        __syncthreads();   // drains the h_buf stores (vmcnt) for all threads

        if (tid == 0) {
            __threadfence();
            __hip_atomic_store(&slots[w], t + 1, __ATOMIC_RELEASE,
                               __HIP_MEMORY_SCOPE_AGENT);
        }
    }
}

// ---------------- K4: batched W_out GEMM + per-block softmax partials -------
__global__ __launch_bounds__(256) void k_out(
    const float* __restrict__ W_out, const float* __restrict__ b_out,
    const float* __restrict__ h_buf, const int* __restrict__ labels,
    float* __restrict__ pm, float* __restrict__ ps, float* __restrict__ ll)
{
    __shared__ __align__(16) unsigned char smem[256*65*4 + 64*33*4];
    unsigned* h2u = (unsigned*)smem;                  // [256][65] bf16x2, k-pairs
    float* Wt  = (float*)(smem + 256*65*4);           // [64][33]
    float* lg  = (float*)smem;                        // [64][65] (after k-loop)
    float* redb = Wt;                                 // reduction scratch (after loop)

    const int tid = threadIdx.x;
    const int r0 = blockIdx.x * 64;
    const int tq = tid & 15, rq = tid >> 4;

    // stage h2 as packed bf16 pairs, transposed [k2][t]
    for (int i = 0; i < 64; ++i) {
        int p = tid + i * 256;           // [0,16384)
        int t = p >> 8, k2 = p & 255;
        float2 hv = ((const float2*)h_buf)[t * (H_/2) + k2];
        h2u[k2 * 65 + t] = bf16rne(hv.x) | (bf16rne(hv.y) << 16);
    }
    float acc[4][4];
    #pragma unroll
    for (int i = 0; i < 4; ++i)
        #pragma unroll
        for (int j = 0; j < 4; ++j) acc[i][j] = 0.f;
    __syncthreads();

    for (int kt = 0; kt < 16; ++kt) {
        #pragma unroll
        for (int i = 0; i < 2; ++i) {
            int p = tid + i * 256;       // float4 index over [64][32]
            int row = p >> 3, k4 = p & 7;
            int r = r0 + row;
            float4 v = make_float4(0.f, 0.f, 0.f, 0.f);
            if (r < L_) v = ((const float4*)W_out)[r * (H_/4) + kt * 8 + k4];
            float* dst = &Wt[row * 33 + k4 * 4];
            dst[0]=v.x; dst[1]=v.y; dst[2]=v.z; dst[3]=v.w;
        }
        __syncthreads();

        #pragma unroll
        for (int kk = 0; kk < 16; ++kk) {
            int k2 = kt * 16 + kk;
            unsigned hp0 = h2u[k2*65 + tq*4 + 0];
            unsigned hp1 = h2u[k2*65 + tq*4 + 1];
            unsigned hp2 = h2u[k2*65 + tq*4 + 2];
            unsigned hp3 = h2u[k2*65 + tq*4 + 3];
            float f0l = __uint_as_float(hp0 << 16), f0h = __uint_as_float(hp0 & 0xffff0000u);
            float f1l = __uint_as_float(hp1 << 16), f1h = __uint_as_float(hp1 & 0xffff0000u);
            float f2l = __uint_as_float(hp2 << 16), f2h = __uint_as_float(hp2 & 0xffff0000u);
            float f3l = __uint_as_float(hp3 << 16), f3h = __uint_as_float(hp3 & 0xffff0000u);
            #pragma unroll
            for (int i = 0; i < 4; ++i) {
                float w0 = Wt[(rq*4+i)*33 + kk*2 + 0];
                float w1 = Wt[(rq*4+i)*33 + kk*2 + 1];
                acc[i][0] += w0*f0l + w1*f0h;
                acc[i][1] += w0*f1l + w1*f1h;
                acc[i][2] += w0*f2l + w1*f2h;
                acc[i][3] += w0*f3l + w1*f3h;
            }
        }
        __syncthreads();
    }

    // logits to LDS (reuse h2 area)
    #pragma unroll
    for (int i = 0; i < 4; ++i) {
        int r = r0 + rq * 4 + i;
        float bo = (r < L_) ? b_out[r] : 0.f;
        #pragma unroll
        for (int j = 0; j < 4; ++j) {
            float v = (r < L_) ? (acc[i][j] + bo) : -1e30f;
            lg[(rq*4+i)*65 + tq*4 + j] = v;
        }
    }
    __syncthreads();

    const int t = tid & 63, part = tid >> 6;
    float m = -1e30f;
    #pragma unroll
    for (int r16 = 0; r16 < 16; ++r16)
        m = fmaxf(m, lg[(part*16 + r16)*65 + t]);
    redb[part*64 + t] = m;
    __syncthreads();
    float* gmax = redb + 256;
    if (part == 0)
        gmax[t] = fmaxf(fmaxf(redb[t], redb[64+t]), fmaxf(redb[128+t], redb[192+t]));
    __syncthreads();
    float gm = gmax[t];
    float s = 0.f;
    #pragma unroll
    for (int r16 = 0; r16 < 16; ++r16)
        s += __expf(lg[(part*16 + r16)*65 + t] - gm);
    __syncthreads();
    redb[part*64 + t] = s;
    __syncthreads();
    if (part == 0) {
        pm[t * NBP_ + blockIdx.x] = gm;
        ps[t * NBP_ + blockIdx.x] = redb[t] + redb[64+t] + redb[128+t] + redb[192+t];
        int lb = labels[t];
        if (lb >= r0 && lb < r0 + 64) ll[t] = lg[(lb - r0)*65 + t];
    }
}

// ---------------- K5: combine partials, NLL, total loss ---------------------
__global__ __launch_bounds__(256) void k_final(
    const float* __restrict__ pm, const float* __restrict__ ps,
    const float* __restrict__ ll, const int* __restrict__ labels,
    float* __restrict__ out)
{
    __shared__ float rbuf[8];
    const int t = blockIdx.x, tid = threadIdx.x;
    float m = -1e30f;
    for (int b = tid; b < NB_; b += 256) m = fmaxf(m, pm[t * NBP_ + b]);
    for (int off = 32; off; off >>= 1) m = fmaxf(m, __shfl_down(m, off));
    if ((tid & 63) == 0) rbuf[tid >> 6] = m;
    __syncthreads();
    if (tid == 0) rbuf[4] = fmaxf(fmaxf(rbuf[0], rbuf[1]), fmaxf(rbuf[2], rbuf[3]));
    __syncthreads();
    float M = rbuf[4];
    __syncthreads();
    float s = 0.f;
    for (int b = tid; b < NB_; b += 256)
        s += ps[t * NBP_ + b] * __expf(pm[t * NBP_ + b] - M);
    for (int off = 32; off; off >>= 1) s += __shfl_down(s, off);
    if ((tid & 63) == 0) rbuf[tid >> 6] = s;
    __syncthreads();
    if (tid == 0) {
        float S = rbuf[0] + rbuf[1] + rbuf[2] + rbuf[3];
        int lb = labels[t];
        if (lb != 0) {
            float loss = -(ll[t] - M - __logf(S));
            atomicAdd(out, loss);
        }
    }
}

extern "C" void kernel_launch(void* const* d_in, const int* in_sizes, int n_in,
                              void* d_out, int out_size, void* d_ws, size_t ws_size,
                              hipStream_t stream)
{
    (void)in_sizes; (void)n_in; (void)out_size; (void)ws_size;
    const float* enc    = (const float*)d_in[0];
    const float* h0     = (const float*)d_in[1];
    const float* c0     = (const float*)d_in[2];
    const float* emb    = (const float*)d_in[3];
    const float* W_attn = (const float*)d_in[4];
    const float* b_attn = (const float*)d_in[5];
    const float* W_ih   = (const float*)d_in[6];
    const float* W_hh   = (const float*)d_in[7];
    const float* b_ih   = (const float*)d_in[8];
    const float* b_hh   = (const float*)d_in[9];
    const float* W_out  = (const float*)d_in[10];
    const float* b_out  = (const float*)d_in[11];
    const int* widx     = (const int*)d_in[12];
    const int* labels   = (const int*)d_in[13];
    float* out = (float*)d_out;

    char* ws = (char*)d_ws;
    float* ctx   = (float*)(ws + 0);          // 64*512*4      = 131072
    float* A_pre = (float*)(ws + 131072);     // 64*2048*4     = 524288
    float* h_buf = (float*)(ws + 655360);     // 64*512*4      = 131072
    int*   slots = (int*)(ws + 786432);       // 32*4 (pad 256)
    float* pm    = (float*)(ws + 786688);     // 64*784*4      = 200704
    float* ps    = (float*)(ws + 987392);     // 64*784*4      = 200704
    float* ll    = (float*)(ws + 1188096);    // 64*4

    hipMemsetAsync(slots, 0, NWG_ * sizeof(int), stream);
    hipMemsetAsync(out, 0, sizeof(float), stream);

    k_attn<<<T_, 256, 0, stream>>>(enc, emb, W_attn, b_attn, widx, ctx);
    k_gatepre<<<256, 256, 0, stream>>>(ctx, W_ih, b_ih, b_hh, A_pre);
    k_lstm<<<NWG_, 256, 0, stream>>>(W_hh, A_pre, h0, c0, h_buf, slots);
    k_out<<<NB_, 256, 0, stream>>>(W_out, b_out, h_buf, labels, pm, ps, ll);
    k_final<<<T_, 256, 0, stream>>>(pm, ps, ll, labels, out);
}

// Round 2
// 373.309 us; speedup vs baseline: 1.3827x; 1.3827x over previous
//
#include <hip/hip_runtime.h>
#include <hip/hip_bf16.h>

#define V_ 100000
#define E_ 256
#define H_ 512
#define L_ 50000
#define S_ 512
#define T_ 64
#define NB_ 782        // ceil(L/64)
#define NBP_ 784
#define NWG_ 32

__device__ __forceinline__ float sigm(float x){ return 1.0f/(1.0f+__expf(-x)); }
__device__ __forceinline__ unsigned bf16rne(float x){
    unsigned u = __float_as_uint(x);
    return (u + 0x7fffu + ((u >> 16) & 1u)) >> 16;
}

// ---------------- K1: per-step attention (embed -> q -> softmax -> ctx) ----
__global__ __launch_bounds__(256) void k_attn(
    const float* __restrict__ enc, const float* __restrict__ emb,
    const float* __restrict__ W_attn, const float* __restrict__ b_attn,
    const int* __restrict__ word_inputs, float* __restrict__ ctx_out)
{
    __shared__ float e_l[E_];
    __shared__ float q_l[H_];
    __shared__ float sc[S_];
    __shared__ float red[8];
    const int t = blockIdx.x, tid = threadIdx.x;
    const int widx = word_inputs[t];

    e_l[tid] = emb[(long)widx * E_ + tid];
    __syncthreads();

    // q = W_attn @ e + b_attn  (each thread 2 rows)
    for (int rr = 0; rr < 2; ++rr) {
        int r = tid + rr * 256;
        const float4* wrow = (const float4*)(W_attn + r * E_);
        const float4* ev = (const float4*)e_l;
        float acc = b_attn[r];
        #pragma unroll 8
        for (int j = 0; j < E_ / 4; ++j) {
            float4 w = wrow[j], e4 = ev[j];
            acc += w.x*e4.x + w.y*e4.y + w.z*e4.z + w.w*e4.w;
        }
        q_l[r] = acc;
    }
    __syncthreads();

    // scores[s] = enc[s] . q
    for (int rr = 0; rr < 2; ++rr) {
        int s = tid + rr * 256;
        const float4* er = (const float4*)(enc + s * H_);
        const float4* qv = (const float4*)q_l;
        float acc = 0.f;
        #pragma unroll 8
        for (int j = 0; j < H_ / 4; ++j) {
            float4 a = er[j], b = qv[j];
            acc += a.x*b.x + a.y*b.y + a.z*b.z + a.w*b.w;
        }
        sc[s] = acc;
    }
    __syncthreads();

    // softmax over 512
    float m = fmaxf(sc[tid], sc[tid + 256]);
    for (int off = 32; off; off >>= 1) m = fmaxf(m, __shfl_down(m, off));
    if ((tid & 63) == 0) red[tid >> 6] = m;
    __syncthreads();
    if (tid == 0) red[4] = fmaxf(fmaxf(red[0], red[1]), fmaxf(red[2], red[3]));
    __syncthreads();
    m = red[4];
    float e0 = __expf(sc[tid] - m), e1 = __expf(sc[tid + 256] - m);
    sc[tid] = e0; sc[tid + 256] = e1;
    float ssum = e0 + e1;
    for (int off = 32; off; off >>= 1) ssum += __shfl_down(ssum, off);
    if ((tid & 63) == 0) red[tid >> 6] = ssum;
    __syncthreads();
    if (tid == 0) red[5] = red[0] + red[1] + red[2] + red[3];
    __syncthreads();
    float inv = 1.0f / red[5];

    // ctx[h] = sum_s alpha[s] * enc[s][h]   (coalesced over h)
    for (int rr = 0; rr < 2; ++rr) {
        int h = tid + rr * 256;
        float acc = 0.f;
        #pragma unroll 4
        for (int s = 0; s < S_; ++s) acc += sc[s] * enc[s * H_ + h];
        ctx_out[t * H_ + h] = acc * inv;
    }
}

// ---------------- K2: A[t] = W_ih @ ctx_t + b_ih + b_hh ---------------------
__global__ __launch_bounds__(256) void k_gatepre(
    const float* __restrict__ ctx, const float* __restrict__ W_ih,
    const float* __restrict__ b_ih, const float* __restrict__ b_hh,
    float* __restrict__ A_pre)
{
    __shared__ float ctx_t[H_ * 65];   // transposed [k][t], stride 65 (bank-safe)
    __shared__ float w_l[8 * H_];
    const int tid = threadIdx.x;
    const int r0 = blockIdx.x * 8;

    for (int i = 0; i < 32; ++i) {
        int p = tid + i * 256;             // float4 index over [64][512]
        int t = p >> 7, k4 = p & 127;
        float4 v = ((const float4*)ctx)[p];
        ctx_t[(k4*4+0)*65 + t] = v.x;
        ctx_t[(k4*4+1)*65 + t] = v.y;
        ctx_t[(k4*4+2)*65 + t] = v.z;
        ctx_t[(k4*4+3)*65 + t] = v.w;
    }
    for (int i = 0; i < 4; ++i) {
        int p = tid + i * 256;             // float4 index over [8][512]
        int row = p >> 7, k4 = p & 127;
        float4 v = ((const float4*)W_ih)[(r0 + row) * (H_/4) + k4];
        float* dst = &w_l[row * H_ + k4 * 4];
        dst[0]=v.x; dst[1]=v.y; dst[2]=v.z; dst[3]=v.w;
    }
    __syncthreads();

    const int t = tid & 63, half = tid >> 6;
    const float* w0 = &w_l[(half*2+0) * H_];
    const float* w1 = &w_l[(half*2+1) * H_];
    float acc0 = 0.f, acc1 = 0.f;
    #pragma unroll 4
    for (int k = 0; k < H_; ++k) {
        float cv = ctx_t[k * 65 + t];
        acc0 += w0[k] * cv;
        acc1 += w1[k] * cv;
    }
    int ra = r0 + half * 2, rb = ra + 1;
    A_pre[t * 2048 + ra] = acc0 + b_ih[ra] + b_hh[ra];
    A_pre[t * 2048 + rb] = acc1 + b_ih[rb] + b_hh[rb];
}

// ---------------- K3: persistent sequential LSTM (32 WGs, data-as-flag) -----
// thread = (row r in [0,64), kslice ks in [0,4)); W_hh slice lives in VGPRs.
__global__ __launch_bounds__(256, 1) void k_lstm(
    const float* __restrict__ W_hh, const float* __restrict__ A_pre,
    const float* __restrict__ h0, const float* __restrict__ c0,
    float* __restrict__ h_buf)
{
    __shared__ float h_l[H_];
    __shared__ float A_l[T_ * 64];   // [t][r]
    __shared__ float g_l[64];
    __shared__ float c_l[16];

    const int tid = threadIdx.x, w = blockIdx.x;
    const int base = w * 16;
    const int r = tid >> 2, ks = tid & 3;
    const int G = ((r >> 4) << 9) + base + (r & 15);   // global gate-row index

    // W slice -> 128 VGPRs (32 x float4), fully unrolled (static indexing)
    float4 w4[32];
    const float4* wsrc = (const float4*)(W_hh + (long)G * H_ + ks * 128);
    #pragma unroll
    for (int i = 0; i < 32; ++i) w4[i] = wsrc[i];

    // A_pre slice -> LDS (off critical path)
    for (int i = 0; i < 16; ++i) {
        int p = tid + i * 256;          // [0, 4096)
        int t = p >> 6, rr = p & 63;
        A_l[p] = A_pre[t * 2048 + ((rr >> 4) << 9) + base + (rr & 15)];
    }
    if (tid < 16) c_l[tid] = c0[base + tid];

    const unsigned SENT = 0xFFFFFFFFu;

    for (int t = 0; t < T_; ++t) {
        if (t == 0) {
            h_l[tid]       = h0[tid];
            h_l[tid + 256] = h0[tid + 256];
        } else {
            const unsigned* hb = (const unsigned*)h_buf + (t - 1) * H_;
            unsigned u0 = __hip_atomic_load(hb + tid, __ATOMIC_RELAXED,
                                            __HIP_MEMORY_SCOPE_AGENT);
            unsigned u1 = __hip_atomic_load(hb + tid + 256, __ATOMIC_RELAXED,
                                            __HIP_MEMORY_SCOPE_AGENT);
            while (u0 == SENT) {
                __builtin_amdgcn_s_sleep(1);
                u0 = __hip_atomic_load(hb + tid, __ATOMIC_RELAXED,
                                       __HIP_MEMORY_SCOPE_AGENT);
            }
            while (u1 == SENT) {
                __builtin_amdgcn_s_sleep(1);
                u1 = __hip_atomic_load(hb + tid + 256, __ATOMIC_RELAXED,
                                       __HIP_MEMORY_SCOPE_AGENT);
            }
            h_l[tid]       = __uint_as_float(u0);
            h_l[tid + 256] = __uint_as_float(u1);
        }
        __syncthreads();   // h_l (and first-iter A_l/c_l staging) visible

        const float4* hp = (const float4*)h_l + ks * 32;
        float a0 = 0.f, a1 = 0.f, a2 = 0.f, a3 = 0.f;
        #pragma unroll
        for (int i = 0; i < 32; i += 4) {
            float4 hA = hp[i+0], hB = hp[i+1], hC = hp[i+2], hD = hp[i+3];
            a0 += w4[i+0].x*hA.x + w4[i+0].y*hA.y + w4[i+0].z*hA.z + w4[i+0].w*hA.w;
            a1 += w4[i+1].x*hB.x + w4[i+1].y*hB.y + w4[i+1].z*hB.z + w4[i+1].w*hB.w;
            a2 += w4[i+2].x*hC.x + w4[i+2].y*hC.y + w4[i+2].z*hC.z + w4[i+2].w*hC.w;
            a3 += w4[i+3].x*hD.x + w4[i+3].y*hD.y + w4[i+3].z*hD.z + w4[i+3].w*hD.w;
        }
        float acc = (a0 + a1) + (a2 + a3);
        acc += __shfl_xor(acc, 1);
        acc += __shfl_xor(acc, 2);
        if (ks == 0) g_l[r] = acc + A_l[t * 64 + r];
        __syncthreads();

        if (tid < 16) {
            float gi = sigm(g_l[tid]);
            float gf = sigm(g_l[16 + tid]);
            float gg = tanhf(g_l[32 + tid]);
            float go = sigm(g_l[48 + tid]);
            float c2 = gf * c_l[tid] + gi * gg;
            c_l[tid] = c2;
            float h2 = go * tanhf(c2);
            __hip_atomic_store((unsigned*)h_buf + t * H_ + base + tid,
                               __float_as_uint(h2),
                               __ATOMIC_RELAXED, __HIP_MEMORY_SCOPE_AGENT);
        }
        // no trailing barrier: next-iter poll self-synchronizes via the data
    }
}

// ---------------- K4: batched W_out GEMM + per-block softmax partials -------
__global__ __launch_bounds__(256) void k_out(
    const float* __restrict__ W_out, const float* __restrict__ b_out,
    const float* __restrict__ h_buf, const int* __restrict__ labels,
    float* __restrict__ pm, float* __restrict__ ps, float* __restrict__ ll)
{
    __shared__ __align__(16) unsigned char smem[256*65*4 + 64*33*4];
    unsigned* h2u = (unsigned*)smem;                  // [256][65] bf16x2, k-pairs
    float* Wt  = (float*)(smem + 256*65*4);           // [64][33]
    float* lg  = (float*)smem;                        // [64][65] (after k-loop)
    float* redb = Wt;                                 // reduction scratch (after loop)

    const int tid = threadIdx.x;
    const int r0 = blockIdx.x * 64;
    const int tq = tid & 15, rq = tid >> 4;

    // stage h2 as packed bf16 pairs, transposed [k2][t]
    for (int i = 0; i < 64; ++i) {
        int p = tid + i * 256;           // [0,16384)
        int t = p >> 8, k2 = p & 255;
        float2 hv = ((const float2*)h_buf)[t * (H_/2) + k2];
        h2u[k2 * 65 + t] = bf16rne(hv.x) | (bf16rne(hv.y) << 16);
    }
    float acc[4][4];
    #pragma unroll
    for (int i = 0; i < 4; ++i)
        #pragma unroll
        for (int j = 0; j < 4; ++j) acc[i][j] = 0.f;
    __syncthreads();

    for (int kt = 0; kt < 16; ++kt) {
        #pragma unroll
        for (int i = 0; i < 2; ++i) {
            int p = tid + i * 256;       // float4 index over [64][32]
            int row = p >> 3, k4 = p & 7;
            int r = r0 + row;
            float4 v = make_float4(0.f, 0.f, 0.f, 0.f);
            if (r < L_) v = ((const float4*)W_out)[r * (H_/4) + kt * 8 + k4];
            float* dst = &Wt[row * 33 + k4 * 4];
            dst[0]=v.x; dst[1]=v.y; dst[2]=v.z; dst[3]=v.w;
        }
        __syncthreads();

        #pragma unroll
        for (int kk = 0; kk < 16; ++kk) {
            int k2 = kt * 16 + kk;
            unsigned hp0 = h2u[k2*65 + tq*4 + 0];
            unsigned hp1 = h2u[k2*65 + tq*4 + 1];
            unsigned hp2 = h2u[k2*65 + tq*4 + 2];
            unsigned hp3 = h2u[k2*65 + tq*4 + 3];
            float f0l = __uint_as_float(hp0 << 16), f0h = __uint_as_float(hp0 & 0xffff0000u);
            float f1l = __uint_as_float(hp1 << 16), f1h = __uint_as_float(hp1 & 0xffff0000u);
            float f2l = __uint_as_float(hp2 << 16), f2h = __uint_as_float(hp2 & 0xffff0000u);
            float f3l = __uint_as_float(hp3 << 16), f3h = __uint_as_float(hp3 & 0xffff0000u);
            #pragma unroll
            for (int i = 0; i < 4; ++i) {
                float w0 = Wt[(rq*4+i)*33 + kk*2 + 0];
                float w1 = Wt[(rq*4+i)*33 + kk*2 + 1];
                acc[i][0] += w0*f0l + w1*f0h;
                acc[i][1] += w0*f1l + w1*f1h;
                acc[i][2] += w0*f2l + w1*f2h;
                acc[i][3] += w0*f3l + w1*f3h;
            }
        }
        __syncthreads();
    }

    // logits to LDS (reuse h2 area)
    #pragma unroll
    for (int i = 0; i < 4; ++i) {
        int r = r0 + rq * 4 + i;
        float bo = (r < L_) ? b_out[r] : 0.f;
        #pragma unroll
        for (int j = 0; j < 4; ++j) {
            float v = (r < L_) ? (acc[i][j] + bo) : -1e30f;
            lg[(rq*4+i)*65 + tq*4 + j] = v;
        }
    }
    __syncthreads();

    const int t = tid & 63, part = tid >> 6;
    float m = -1e30f;
    #pragma unroll
    for (int r16 = 0; r16 < 16; ++r16)
        m = fmaxf(m, lg[(part*16 + r16)*65 + t]);
    redb[part*64 + t] = m;
    __syncthreads();
    float* gmax = redb + 256;
    if (part == 0)
        gmax[t] = fmaxf(fmaxf(redb[t], redb[64+t]), fmaxf(redb[128+t], redb[192+t]));
    __syncthreads();
    float gm = gmax[t];
    float s = 0.f;
    #pragma unroll
    for (int r16 = 0; r16 < 16; ++r16)
        s += __expf(lg[(part*16 + r16)*65 + t] - gm);
    __syncthreads();
    redb[part*64 + t] = s;
    __syncthreads();
    if (part == 0) {
        pm[t * NBP_ + blockIdx.x] = gm;
        ps[t * NBP_ + blockIdx.x] = redb[t] + redb[64+t] + redb[128+t] + redb[192+t];
        int lb = labels[t];
        if (lb >= r0 && lb < r0 + 64) ll[t] = lg[(lb - r0)*65 + t];
    }
}

// ---------------- K5: combine partials, NLL, total loss ---------------------
__global__ __launch_bounds__(256) void k_final(
    const float* __restrict__ pm, const float* __restrict__ ps,
    const float* __restrict__ ll, const int* __restrict__ labels,
    float* __restrict__ out)
{
    __shared__ float rbuf[8];
    const int t = blockIdx.x, tid = threadIdx.x;
    float m = -1e30f;
    for (int b = tid; b < NB_; b += 256) m = fmaxf(m, pm[t * NBP_ + b]);
    for (int off = 32; off; off >>= 1) m = fmaxf(m, __shfl_down(m, off));
    if ((tid & 63) == 0) rbuf[tid >> 6] = m;
    __syncthreads();
    if (tid == 0) rbuf[4] = fmaxf(fmaxf(rbuf[0], rbuf[1]), fmaxf(rbuf[2], rbuf[3]));
    __syncthreads();
    float M = rbuf[4];
    __syncthreads();
    float s = 0.f;
    for (int b = tid; b < NB_; b += 256)
        s += ps[t * NBP_ + b] * __expf(pm[t * NBP_ + b] - M);
    for (int off = 32; off; off >>= 1) s += __shfl_down(s, off);
    if ((tid & 63) == 0) rbuf[tid >> 6] = s;
    __syncthreads();
    if (tid == 0) {
        float S = rbuf[0] + rbuf[1] + rbuf[2] + rbuf[3];
        int lb = labels[t];
        if (lb != 0) {
            float loss = -(ll[t] - M - __logf(S));
            atomicAdd(out, loss);
        }
    }
}

extern "C" void kernel_launch(void* const* d_in, const int* in_sizes, int n_in,
                              void* d_out, int out_size, void* d_ws, size_t ws_size,
                              hipStream_t stream)
{
    (void)in_sizes; (void)n_in; (void)out_size; (void)ws_size;
    const float* enc    = (const float*)d_in[0];
    const float* h0     = (const float*)d_in[1];
    const float* c0     = (const float*)d_in[2];
    const float* emb    = (const float*)d_in[3];
    const float* W_attn = (const float*)d_in[4];
    const float* b_attn = (const float*)d_in[5];
    const float* W_ih   = (const float*)d_in[6];
    const float* W_hh   = (const float*)d_in[7];
    const float* b_ih   = (const float*)d_in[8];
    const float* b_hh   = (const float*)d_in[9];
    const float* W_out  = (const float*)d_in[10];
    const float* b_out  = (const float*)d_in[11];
    const int* widx     = (const int*)d_in[12];
    const int* labels   = (const int*)d_in[13];
    float* out = (float*)d_out;

    char* ws = (char*)d_ws;
    float* ctx   = (float*)(ws + 0);          // 64*512*4      = 131072
    float* A_pre = (float*)(ws + 131072);     // 64*2048*4     = 524288
    float* h_buf = (float*)(ws + 655360);     // 64*512*4      = 131072
    float* pm    = (float*)(ws + 786688);     // 64*784*4      = 200704
    float* ps    = (float*)(ws + 987392);     // 64*784*4      = 200704
    float* ll    = (float*)(ws + 1188096);    // 64*4

    hipMemsetAsync(h_buf, 0xFF, T_ * H_ * sizeof(float), stream);  // sentinel
    hipMemsetAsync(out, 0, sizeof(float), stream);

    k_attn<<<T_, 256, 0, stream>>>(enc, emb, W_attn, b_attn, widx, ctx);
    k_gatepre<<<256, 256, 0, stream>>>(ctx, W_ih, b_ih, b_hh, A_pre);
    k_lstm<<<NWG_, 256, 0, stream>>>(W_hh, A_pre, h0, c0, h_buf);
    k_out<<<NB_, 256, 0, stream>>>(W_out, b_out, h_buf, labels, pm, ps, ll);
    k_final<<<T_, 256, 0, stream>>>(pm, ps, ll, labels, out);
}

// Round 3
// 331.402 us; speedup vs baseline: 1.5575x; 1.1265x over previous
//
#include <hip/hip_runtime.h>
#include <hip/hip_bf16.h>

#define V_ 100000
#define E_ 256
#define H_ 512
#define L_ 50000
#define S_ 512
#define T_ 64
#define NB_ 782        // ceil(L/64)
#define NBP_ 784
#define NWG_ 32

__device__ __forceinline__ float sigm(float x){ return 1.0f/(1.0f+__expf(-x)); }
__device__ __forceinline__ float tanh_fast(float x){
    x = fminf(fmaxf(x, -15.f), 15.f);
    float e = __expf(2.f * x);
    return __fdividef(e - 1.f, e + 1.f);
}
__device__ __forceinline__ unsigned bf16rne(float x){
    unsigned u = __float_as_uint(x);
    return (u + 0x7fffu + ((u >> 16) & 1u)) >> 16;
}
__device__ __forceinline__ float bcast(float v, int l){
    return __uint_as_float(__builtin_amdgcn_readlane(__float_as_uint(v), l));
}

// ---------------- K1: per-step attention (embed -> q -> softmax -> ctx) ----
__global__ __launch_bounds__(256) void k_attn(
    const float* __restrict__ enc, const float* __restrict__ emb,
    const float* __restrict__ W_attn, const float* __restrict__ b_attn,
    const int* __restrict__ word_inputs, float* __restrict__ ctx_out)
{
    __shared__ float e_l[E_];
    __shared__ float q_l[H_];
    __shared__ float sc[S_];
    __shared__ float red[8];
    const int t = blockIdx.x, tid = threadIdx.x;
    const int widx = word_inputs[t];

    e_l[tid] = emb[(long)widx * E_ + tid];
    __syncthreads();

    for (int rr = 0; rr < 2; ++rr) {
        int r = tid + rr * 256;
        const float4* wrow = (const float4*)(W_attn + r * E_);
        const float4* ev = (const float4*)e_l;
        float acc = b_attn[r];
        #pragma unroll 8
        for (int j = 0; j < E_ / 4; ++j) {
            float4 w = wrow[j], e4 = ev[j];
            acc += w.x*e4.x + w.y*e4.y + w.z*e4.z + w.w*e4.w;
        }
        q_l[r] = acc;
    }
    __syncthreads();

    for (int rr = 0; rr < 2; ++rr) {
        int s = tid + rr * 256;
        const float4* er = (const float4*)(enc + s * H_);
        const float4* qv = (const float4*)q_l;
        float acc = 0.f;
        #pragma unroll 8
        for (int j = 0; j < H_ / 4; ++j) {
            float4 a = er[j], b = qv[j];
            acc += a.x*b.x + a.y*b.y + a.z*b.z + a.w*b.w;
        }
        sc[s] = acc;
    }
    __syncthreads();

    float m = fmaxf(sc[tid], sc[tid + 256]);
    for (int off = 32; off; off >>= 1) m = fmaxf(m, __shfl_down(m, off));
    if ((tid & 63) == 0) red[tid >> 6] = m;
    __syncthreads();
    if (tid == 0) red[4] = fmaxf(fmaxf(red[0], red[1]), fmaxf(red[2], red[3]));
    __syncthreads();
    m = red[4];
    float e0 = __expf(sc[tid] - m), e1 = __expf(sc[tid + 256] - m);
    sc[tid] = e0; sc[tid + 256] = e1;
    float ssum = e0 + e1;
    for (int off = 32; off; off >>= 1) ssum += __shfl_down(ssum, off);
    if ((tid & 63) == 0) red[tid >> 6] = ssum;
    __syncthreads();
    if (tid == 0) red[5] = red[0] + red[1] + red[2] + red[3];
    __syncthreads();
    float inv = 1.0f / red[5];

    for (int rr = 0; rr < 2; ++rr) {
        int h = tid + rr * 256;
        float acc = 0.f;
        #pragma unroll 4
        for (int s = 0; s < S_; ++s) acc += sc[s] * enc[s * H_ + h];
        ctx_out[t * H_ + h] = acc * inv;
    }
}

// ---------------- K2: A[t] = W_ih @ ctx_t + b_ih + b_hh ---------------------
__global__ __launch_bounds__(256) void k_gatepre(
    const float* __restrict__ ctx, const float* __restrict__ W_ih,
    const float* __restrict__ b_ih, const float* __restrict__ b_hh,
    float* __restrict__ A_pre)
{
    __shared__ float ctx_t[H_ * 65];   // transposed [k][t], stride 65
    __shared__ float w_l[8 * H_];
    const int tid = threadIdx.x;
    const int r0 = blockIdx.x * 8;

    for (int i = 0; i < 32; ++i) {
        int p = tid + i * 256;
        int t = p >> 7, k4 = p & 127;
        float4 v = ((const float4*)ctx)[p];
        ctx_t[(k4*4+0)*65 + t] = v.x;
        ctx_t[(k4*4+1)*65 + t] = v.y;
        ctx_t[(k4*4+2)*65 + t] = v.z;
        ctx_t[(k4*4+3)*65 + t] = v.w;
    }
    for (int i = 0; i < 4; ++i) {
        int p = tid + i * 256;
        int row = p >> 7, k4 = p & 127;
        float4 v = ((const float4*)W_ih)[(r0 + row) * (H_/4) + k4];
        float* dst = &w_l[row * H_ + k4 * 4];
        dst[0]=v.x; dst[1]=v.y; dst[2]=v.z; dst[3]=v.w;
    }
    __syncthreads();

    const int t = tid & 63, half = tid >> 6;
    const float* w0 = &w_l[(half*2+0) * H_];
    const float* w1 = &w_l[(half*2+1) * H_];
    float acc0 = 0.f, acc1 = 0.f;
    #pragma unroll 4
    for (int k = 0; k < H_; ++k) {
        float cv = ctx_t[k * 65 + t];
        acc0 += w0[k] * cv;
        acc1 += w1[k] * cv;
    }
    int ra = r0 + half * 2, rb = ra + 1;
    A_pre[t * 2048 + ra] = acc0 + b_ih[ra] + b_hh[ra];
    A_pre[t * 2048 + rb] = acc1 + b_ih[rb] + b_hh[rb];
}

// ---------------- K3: persistent LSTM — W in VGPRs, h via readlane ----------
// wave = k-slice ks (0..3); lane = gate-row r (0..63) of this WG's 64 rows.
__global__ __launch_bounds__(256, 1) void k_lstm(
    const float* __restrict__ W_hh, const float* __restrict__ A_pre,
    const float* __restrict__ h0, const float* __restrict__ c0,
    float* __restrict__ h_buf)
{
    __shared__ float A_l[T_ * 64];      // [t][r]
    __shared__ float red[2][4][64];     // [parity][ks][r]

    const int tid = threadIdx.x, w = blockIdx.x;
    const int base = w * 16;
    const int lane = tid & 63;
    const int ks   = tid >> 6;
    const int G = ((lane >> 4) << 9) + base + (lane & 15);  // global gate row

    // W slice -> 128 VGPRs, pinned against rematerialization
    float wr[128];
    {
        const float4* wsrc = (const float4*)(W_hh + (long)G * H_ + ks * 128);
        #pragma unroll
        for (int i = 0; i < 32; ++i) {
            float4 v = wsrc[i];
            wr[4*i+0]=v.x; wr[4*i+1]=v.y; wr[4*i+2]=v.z; wr[4*i+3]=v.w;
        }
    }
    #pragma unroll
    for (int i = 0; i < 128; ++i) asm volatile("" : "+v"(wr[i]));

    // A_pre slice -> LDS (off critical path)
    for (int i = 0; i < 16; ++i) {
        int p = tid + i * 256;          // [0, 4096)
        int tt = p >> 6, rr = p & 63;
        A_l[p] = A_pre[tt * 2048 + ((rr >> 4) << 9) + base + (rr & 15)];
    }
    float c_reg = 0.f;
    if (tid < 16) c_reg = c0[base + tid];

    const unsigned SENT = 0xFFFFFFFFu;

    for (int t = 0; t < T_; ++t) {
        float vh0f, vh1f;
        if (t == 0) {
            vh0f = h0[ks * 128 + lane];
            vh1f = h0[ks * 128 + 64 + lane];
            __syncthreads();            // A_l / first-use ordering
        } else {
            const unsigned* hb = (const unsigned*)h_buf + (t - 1) * H_ + ks * 128;
            unsigned u0 = __hip_atomic_load(hb + lane, __ATOMIC_RELAXED,
                                            __HIP_MEMORY_SCOPE_AGENT);
            while (u0 == SENT) {
                __builtin_amdgcn_s_sleep(1);
                u0 = __hip_atomic_load(hb + lane, __ATOMIC_RELAXED,
                                       __HIP_MEMORY_SCOPE_AGENT);
            }
            unsigned u1 = __hip_atomic_load(hb + 64 + lane, __ATOMIC_RELAXED,
                                            __HIP_MEMORY_SCOPE_AGENT);
            while (u1 == SENT) {
                __builtin_amdgcn_s_sleep(1);
                u1 = __hip_atomic_load(hb + 64 + lane, __ATOMIC_RELAXED,
                                       __HIP_MEMORY_SCOPE_AGENT);
            }
            vh0f = __uint_as_float(u0);
            vh1f = __uint_as_float(u1);
        }

        // partial dot over this wave's 128-k slice; h broadcast via readlane
        float a0 = 0.f, a1 = 0.f, a2 = 0.f, a3 = 0.f;
        #pragma unroll
        for (int k = 0; k < 64; k += 4) {
            a0 += bcast(vh0f, k+0) * wr[k+0];
            a1 += bcast(vh0f, k+1) * wr[k+1];
            a2 += bcast(vh0f, k+2) * wr[k+2];
            a3 += bcast(vh0f, k+3) * wr[k+3];
        }
        #pragma unroll
        for (int k = 0; k < 64; k += 4) {
            a0 += bcast(vh1f, k+0) * wr[64+k+0];
            a1 += bcast(vh1f, k+1) * wr[64+k+1];
            a2 += bcast(vh1f, k+2) * wr[64+k+2];
            a3 += bcast(vh1f, k+3) * wr[64+k+3];
        }
        red[t & 1][ks][lane] = (a0 + a1) + (a2 + a3);
        __syncthreads();

        if (tid < 16) {                 // wave 0, lanes 0..15: finalize unit
            float g4[4];
            #pragma unroll
            for (int g = 0; g < 4; ++g) {
                int r = g * 16 + lane;
                g4[g] = red[t & 1][0][r] + red[t & 1][1][r]
                      + red[t & 1][2][r] + red[t & 1][3][r]
                      + A_l[t * 64 + r];
            }
            float gi = sigm(g4[0]);
            float gf = sigm(g4[1]);
            float gg = tanh_fast(g4[2]);
            float go = sigm(g4[3]);
            float c2 = gf * c_reg + gi * gg;
            c_reg = c2;
            float h2 = go * tanh_fast(c2);
            __hip_atomic_store((unsigned*)h_buf + t * H_ + base + lane,
                               __float_as_uint(h2),
                               __ATOMIC_RELAXED, __HIP_MEMORY_SCOPE_AGENT);
        }
        // no trailing barrier: red is double-buffered; next barrier gates reuse
    }
}

// ---------------- K4: batched W_out GEMM + per-block softmax partials -------
__global__ __launch_bounds__(256) void k_out(
    const float* __restrict__ W_out, const float* __restrict__ b_out,
    const float* __restrict__ h_buf, const int* __restrict__ labels,
    float* __restrict__ pm, float* __restrict__ ps, float* __restrict__ ll)
{
    __shared__ __align__(16) unsigned char smem[256*65*4 + 64*33*4];
    unsigned* h2u = (unsigned*)smem;                  // [256][65] bf16x2
    float* Wt  = (float*)(smem + 256*65*4);           // [64][33]
    float* lg  = (float*)smem;                        // [64][65] (after k-loop)
    float* redb = Wt;

    const int tid = threadIdx.x;
    const int r0 = blockIdx.x * 64;
    const int tq = tid & 15, rq = tid >> 4;

    for (int i = 0; i < 64; ++i) {
        int p = tid + i * 256;
        int t = p >> 8, k2 = p & 255;
        float2 hv = ((const float2*)h_buf)[t * (H_/2) + k2];
        h2u[k2 * 65 + t] = bf16rne(hv.x) | (bf16rne(hv.y) << 16);
    }
    float acc[4][4];
    #pragma unroll
    for (int i = 0; i < 4; ++i)
        #pragma unroll
        for (int j = 0; j < 4; ++j) acc[i][j] = 0.f;
    __syncthreads();

    for (int kt = 0; kt < 16; ++kt) {
        #pragma unroll
        for (int i = 0; i < 2; ++i) {
            int p = tid + i * 256;
            int row = p >> 3, k4 = p & 7;
            int r = r0 + row;
            float4 v = make_float4(0.f, 0.f, 0.f, 0.f);
            if (r < L_) v = ((const float4*)W_out)[r * (H_/4) + kt * 8 + k4];
            float* dst = &Wt[row * 33 + k4 * 4];
            dst[0]=v.x; dst[1]=v.y; dst[2]=v.z; dst[3]=v.w;
        }
        __syncthreads();

        #pragma unroll
        for (int kk = 0; kk < 16; ++kk) {
            int k2 = kt * 16 + kk;
            unsigned hp0 = h2u[k2*65 + tq*4 + 0];
            unsigned hp1 = h2u[k2*65 + tq*4 + 1];
            unsigned hp2 = h2u[k2*65 + tq*4 + 2];
            unsigned hp3 = h2u[k2*65 + tq*4 + 3];
            float f0l = __uint_as_float(hp0 << 16), f0h = __uint_as_float(hp0 & 0xffff0000u);
            float f1l = __uint_as_float(hp1 << 16), f1h = __uint_as_float(hp1 & 0xffff0000u);
            float f2l = __uint_as_float(hp2 << 16), f2h = __uint_as_float(hp2 & 0xffff0000u);
            float f3l = __uint_as_float(hp3 << 16), f3h = __uint_as_float(hp3 & 0xffff0000u);
            #pragma unroll
            for (int i = 0; i < 4; ++i) {
                float w0 = Wt[(rq*4+i)*33 + kk*2 + 0];
                float w1 = Wt[(rq*4+i)*33 + kk*2 + 1];
                acc[i][0] += w0*f0l + w1*f0h;
                acc[i][1] += w0*f1l + w1*f1h;
                acc[i][2] += w0*f2l + w1*f2h;
                acc[i][3] += w0*f3l + w1*f3h;
            }
        }
        __syncthreads();
    }

    #pragma unroll
    for (int i = 0; i < 4; ++i) {
        int r = r0 + rq * 4 + i;
        float bo = (r < L_) ? b_out[r] : 0.f;
        #pragma unroll
        for (int j = 0; j < 4; ++j) {
            float v = (r < L_) ? (acc[i][j] + bo) : -1e30f;
            lg[(rq*4+i)*65 + tq*4 + j] = v;
        }
    }
    __syncthreads();

    const int t = tid & 63, part = tid >> 6;
    float m = -1e30f;
    #pragma unroll
    for (int r16 = 0; r16 < 16; ++r16)
        m = fmaxf(m, lg[(part*16 + r16)*65 + t]);
    redb[part*64 + t] = m;
    __syncthreads();
    float* gmax = redb + 256;
    if (part == 0)
        gmax[t] = fmaxf(fmaxf(redb[t], redb[64+t]), fmaxf(redb[128+t], redb[192+t]));
    __syncthreads();
    float gm = gmax[t];
    float s = 0.f;
    #pragma unroll
    for (int r16 = 0; r16 < 16; ++r16)
        s += __expf(lg[(part*16 + r16)*65 + t] - gm);
    __syncthreads();
    redb[part*64 + t] = s;
    __syncthreads();
    if (part == 0) {
        pm[t * NBP_ + blockIdx.x] = gm;
        ps[t * NBP_ + blockIdx.x] = redb[t] + redb[64+t] + redb[128+t] + redb[192+t];
        int lb = labels[t];
        if (lb >= r0 && lb < r0 + 64) ll[t] = lg[(lb - r0)*65 + t];
    }
}

// ---------------- K5: combine partials, NLL, total loss ---------------------
__global__ __launch_bounds__(256) void k_final(
    const float* __restrict__ pm, const float* __restrict__ ps,
    const float* __restrict__ ll, const int* __restrict__ labels,
    float* __restrict__ out)
{
    __shared__ float rbuf[8];
    const int t = blockIdx.x, tid = threadIdx.x;
    float m = -1e30f;
    for (int b = tid; b < NB_; b += 256) m = fmaxf(m, pm[t * NBP_ + b]);
    for (int off = 32; off; off >>= 1) m = fmaxf(m, __shfl_down(m, off));
    if ((tid & 63) == 0) rbuf[tid >> 6] = m;
    __syncthreads();
    if (tid == 0) rbuf[4] = fmaxf(fmaxf(rbuf[0], rbuf[1]), fmaxf(rbuf[2], rbuf[3]));
    __syncthreads();
    float M = rbuf[4];
    __syncthreads();
    float s = 0.f;
    for (int b = tid; b < NB_; b += 256)
        s += ps[t * NBP_ + b] * __expf(pm[t * NBP_ + b] - M);
    for (int off = 32; off; off >>= 1) s += __shfl_down(s, off);
    if ((tid & 63) == 0) rbuf[tid >> 6] = s;
    __syncthreads();
    if (tid == 0) {
        float S = rbuf[0] + rbuf[1] + rbuf[2] + rbuf[3];
        int lb = labels[t];
        if (lb != 0) {
            float loss = -(ll[t] - M - __logf(S));
            atomicAdd(out, loss);
        }
    }
}

extern "C" void kernel_launch(void* const* d_in, const int* in_sizes, int n_in,
                              void* d_out, int out_size, void* d_ws, size_t ws_size,
                              hipStream_t stream)
{
    (void)in_sizes; (void)n_in; (void)out_size; (void)ws_size;
    const float* enc    = (const float*)d_in[0];
    const float* h0     = (const float*)d_in[1];
    const float* c0     = (const float*)d_in[2];
    const float* emb    = (const float*)d_in[3];
    const float* W_attn = (const float*)d_in[4];
    const float* b_attn = (const float*)d_in[5];
    const float* W_ih   = (const float*)d_in[6];
    const float* W_hh   = (const float*)d_in[7];
    const float* b_ih   = (const float*)d_in[8];
    const float* b_hh   = (const float*)d_in[9];
    const float* W_out  = (const float*)d_in[10];
    const float* b_out  = (const float*)d_in[11];
    const int* widx     = (const int*)d_in[12];
    const int* labels   = (const int*)d_in[13];
    float* out = (float*)d_out;

    char* ws = (char*)d_ws;
    float* ctx   = (float*)(ws + 0);          // 64*512*4      = 131072
    float* A_pre = (float*)(ws + 131072);     // 64*2048*4     = 524288
    float* h_buf = (float*)(ws + 655360);     // 64*512*4      = 131072
    float* pm    = (float*)(ws + 786688);     // 64*784*4      = 200704
    float* ps    = (float*)(ws + 987392);     // 64*784*4      = 200704
    float* ll    = (float*)(ws + 1188096);    // 64*4

    hipMemsetAsync(h_buf, 0xFF, T_ * H_ * sizeof(float), stream);  // sentinel
    hipMemsetAsync(out, 0, sizeof(float), stream);

    k_attn<<<T_, 256, 0, stream>>>(enc, emb, W_attn, b_attn, widx, ctx);
    k_gatepre<<<256, 256, 0, stream>>>(ctx, W_ih, b_ih, b_hh, A_pre);
    k_lstm<<<NWG_, 256, 0, stream>>>(W_hh, A_pre, h0, c0, h_buf);
    k_out<<<NB_, 256, 0, stream>>>(W_out, b_out, h_buf, labels, pm, ps, ll);
    k_final<<<T_, 256, 0, stream>>>(pm, ps, ll, labels, out);
}

// Round 4
// 253.823 us; speedup vs baseline: 2.0336x; 1.3056x over previous
//
#include <hip/hip_runtime.h>
#include <hip/hip_bf16.h>

#define V_ 100000
#define E_ 256
#define H_ 512
#define L_ 50000
#define S_ 512
#define T_ 64
#define NB_ 782        // ceil(L/64)
#define NBP_ 784
#define NWG_ 32

typedef short bf16x8 __attribute__((ext_vector_type(8)));
typedef float f32x4 __attribute__((ext_vector_type(4)));

__device__ __forceinline__ float sigm(float x){ return 1.0f/(1.0f+__expf(-x)); }
__device__ __forceinline__ float tanh_fast(float x){
    x = fminf(fmaxf(x, -15.f), 15.f);
    float e = __expf(2.f * x);
    return __fdividef(e - 1.f, e + 1.f);
}
__device__ __forceinline__ unsigned bf16rne(float x){
    unsigned u = __float_as_uint(x);
    return (u + 0x7fffu + ((u >> 16) & 1u)) >> 16;
}
__device__ __forceinline__ float bcast(float v, int l){
    return __uint_as_float(__builtin_amdgcn_readlane(__float_as_uint(v), l));
}

// ---------------- K1: per-step attention (embed -> q -> softmax -> ctx) ----
__global__ __launch_bounds__(256) void k_attn(
    const float* __restrict__ enc, const float* __restrict__ emb,
    const float* __restrict__ W_attn, const float* __restrict__ b_attn,
    const int* __restrict__ word_inputs, float* __restrict__ ctx_out)
{
    __shared__ float e_l[E_];
    __shared__ float q_l[H_];
    __shared__ float sc[S_];
    __shared__ float red[8];
    const int t = blockIdx.x, tid = threadIdx.x;
    const int widx = word_inputs[t];

    e_l[tid] = emb[(long)widx * E_ + tid];
    __syncthreads();

    for (int rr = 0; rr < 2; ++rr) {
        int r = tid + rr * 256;
        const float4* wrow = (const float4*)(W_attn + r * E_);
        const float4* ev = (const float4*)e_l;
        float acc = b_attn[r];
        #pragma unroll 8
        for (int j = 0; j < E_ / 4; ++j) {
            float4 w = wrow[j], e4 = ev[j];
            acc += w.x*e4.x + w.y*e4.y + w.z*e4.z + w.w*e4.w;
        }
        q_l[r] = acc;
    }
    __syncthreads();

    for (int rr = 0; rr < 2; ++rr) {
        int s = tid + rr * 256;
        const float4* er = (const float4*)(enc + s * H_);
        const float4* qv = (const float4*)q_l;
        float acc = 0.f;
        #pragma unroll 8
        for (int j = 0; j < H_ / 4; ++j) {
            float4 a = er[j], b = qv[j];
            acc += a.x*b.x + a.y*b.y + a.z*b.z + a.w*b.w;
        }
        sc[s] = acc;
    }
    __syncthreads();

    float m = fmaxf(sc[tid], sc[tid + 256]);
    for (int off = 32; off; off >>= 1) m = fmaxf(m, __shfl_down(m, off));
    if ((tid & 63) == 0) red[tid >> 6] = m;
    __syncthreads();
    if (tid == 0) red[4] = fmaxf(fmaxf(red[0], red[1]), fmaxf(red[2], red[3]));
    __syncthreads();
    m = red[4];
    float e0 = __expf(sc[tid] - m), e1 = __expf(sc[tid + 256] - m);
    sc[tid] = e0; sc[tid + 256] = e1;
    float ssum = e0 + e1;
    for (int off = 32; off; off >>= 1) ssum += __shfl_down(ssum, off);
    if ((tid & 63) == 0) red[tid >> 6] = ssum;
    __syncthreads();
    if (tid == 0) red[5] = red[0] + red[1] + red[2] + red[3];
    __syncthreads();
    float inv = 1.0f / red[5];

    for (int rr = 0; rr < 2; ++rr) {
        int h = tid + rr * 256;
        float acc = 0.f;
        #pragma unroll 4
        for (int s = 0; s < S_; ++s) acc += sc[s] * enc[s * H_ + h];
        ctx_out[t * H_ + h] = acc * inv;
    }
}

// ---------------- K2: A[t] = W_ih @ ctx_t + b_ih + b_hh ---------------------
__global__ __launch_bounds__(256) void k_gatepre(
    const float* __restrict__ ctx, const float* __restrict__ W_ih,
    const float* __restrict__ b_ih, const float* __restrict__ b_hh,
    float* __restrict__ A_pre)
{
    __shared__ float ctx_t[H_ * 65];   // transposed [k][t], stride 65
    __shared__ float w_l[8 * H_];
    const int tid = threadIdx.x;
    const int r0 = blockIdx.x * 8;

    for (int i = 0; i < 32; ++i) {
        int p = tid + i * 256;
        int t = p >> 7, k4 = p & 127;
        float4 v = ((const float4*)ctx)[p];
        ctx_t[(k4*4+0)*65 + t] = v.x;
        ctx_t[(k4*4+1)*65 + t] = v.y;
        ctx_t[(k4*4+2)*65 + t] = v.z;
        ctx_t[(k4*4+3)*65 + t] = v.w;
    }
    for (int i = 0; i < 4; ++i) {
        int p = tid + i * 256;
        int row = p >> 7, k4 = p & 127;
        float4 v = ((const float4*)W_ih)[(r0 + row) * (H_/4) + k4];
        float* dst = &w_l[row * H_ + k4 * 4];
        dst[0]=v.x; dst[1]=v.y; dst[2]=v.z; dst[3]=v.w;
    }
    __syncthreads();

    const int t = tid & 63, half = tid >> 6;
    const float* w0 = &w_l[(half*2+0) * H_];
    const float* w1 = &w_l[(half*2+1) * H_];
    float acc0 = 0.f, acc1 = 0.f;
    #pragma unroll 4
    for (int k = 0; k < H_; ++k) {
        float cv = ctx_t[k * 65 + t];
        acc0 += w0[k] * cv;
        acc1 += w1[k] * cv;
    }
    int ra = r0 + half * 2, rb = ra + 1;
    A_pre[t * 2048 + ra] = acc0 + b_ih[ra] + b_hh[ra];
    A_pre[t * 2048 + rb] = acc1 + b_ih[rb] + b_hh[rb];
}

// ---------------- K3: persistent LSTM — W in VGPRs, h via readlane ----------
__global__ __launch_bounds__(256, 1) void k_lstm(
    const float* __restrict__ W_hh, const float* __restrict__ A_pre,
    const float* __restrict__ h0, const float* __restrict__ c0,
    float* __restrict__ h_buf)
{
    __shared__ float A_l[T_ * 64];      // [t][r]
    __shared__ float red[2][4][64];     // [parity][ks][r]

    const int tid = threadIdx.x, w = blockIdx.x;
    const int base = w * 16;
    const int lane = tid & 63;
    const int ks   = tid >> 6;
    const int G = ((lane >> 4) << 9) + base + (lane & 15);  // global gate row

    float wr[128];
    {
        const float4* wsrc = (const float4*)(W_hh + (long)G * H_ + ks * 128);
        #pragma unroll
        for (int i = 0; i < 32; ++i) {
            float4 v = wsrc[i];
            wr[4*i+0]=v.x; wr[4*i+1]=v.y; wr[4*i+2]=v.z; wr[4*i+3]=v.w;
        }
    }
    #pragma unroll
    for (int i = 0; i < 128; ++i) asm volatile("" : "+v"(wr[i]));

    for (int i = 0; i < 16; ++i) {
        int p = tid + i * 256;          // [0, 4096)
        int tt = p >> 6, rr = p & 63;
        A_l[p] = A_pre[tt * 2048 + ((rr >> 4) << 9) + base + (rr & 15)];
    }
    float c_reg = 0.f;
    if (tid < 16) c_reg = c0[base + tid];

    const unsigned SENT = 0xFFFFFFFFu;

    for (int t = 0; t < T_; ++t) {
        float vh0f, vh1f;
        if (t == 0) {
            vh0f = h0[ks * 128 + lane];
            vh1f = h0[ks * 128 + 64 + lane];
            __syncthreads();
        } else {
            const unsigned* hb = (const unsigned*)h_buf + (t - 1) * H_ + ks * 128;
            unsigned u0 = __hip_atomic_load(hb + lane, __ATOMIC_RELAXED,
                                            __HIP_MEMORY_SCOPE_AGENT);
            while (u0 == SENT) {
                __builtin_amdgcn_s_sleep(1);
                u0 = __hip_atomic_load(hb + lane, __ATOMIC_RELAXED,
                                       __HIP_MEMORY_SCOPE_AGENT);
            }
            unsigned u1 = __hip_atomic_load(hb + 64 + lane, __ATOMIC_RELAXED,
                                            __HIP_MEMORY_SCOPE_AGENT);
            while (u1 == SENT) {
                __builtin_amdgcn_s_sleep(1);
                u1 = __hip_atomic_load(hb + 64 + lane, __ATOMIC_RELAXED,
                                       __HIP_MEMORY_SCOPE_AGENT);
            }
            vh0f = __uint_as_float(u0);
            vh1f = __uint_as_float(u1);
        }

        float a0 = 0.f, a1 = 0.f, a2 = 0.f, a3 = 0.f;
        #pragma unroll
        for (int k = 0; k < 64; k += 4) {
            a0 += bcast(vh0f, k+0) * wr[k+0];
            a1 += bcast(vh0f, k+1) * wr[k+1];
            a2 += bcast(vh0f, k+2) * wr[k+2];
            a3 += bcast(vh0f, k+3) * wr[k+3];
        }
        #pragma unroll
        for (int k = 0; k < 64; k += 4) {
            a0 += bcast(vh1f, k+0) * wr[64+k+0];
            a1 += bcast(vh1f, k+1) * wr[64+k+1];
            a2 += bcast(vh1f, k+2) * wr[64+k+2];
            a3 += bcast(vh1f, k+3) * wr[64+k+3];
        }
        red[t & 1][ks][lane] = (a0 + a1) + (a2 + a3);
        __syncthreads();

        if (tid < 16) {
            float g4[4];
            #pragma unroll
            for (int g = 0; g < 4; ++g) {
                int r = g * 16 + lane;
                g4[g] = red[t & 1][0][r] + red[t & 1][1][r]
                      + red[t & 1][2][r] + red[t & 1][3][r]
                      + A_l[t * 64 + r];
            }
            float gi = sigm(g4[0]);
            float gf = sigm(g4[1]);
            float gg = tanh_fast(g4[2]);
            float go = sigm(g4[3]);
            float c2 = gf * c_reg + gi * gg;
            c_reg = c2;
            float h2 = go * tanh_fast(c2);
            __hip_atomic_store((unsigned*)h_buf + t * H_ + base + lane,
                               __float_as_uint(h2),
                               __ATOMIC_RELAXED, __HIP_MEMORY_SCOPE_AGENT);
        }
    }
}

// ---------------- K4: MFMA W_out GEMM + per-block softmax partials ----------
// Block: 64 rows x 64 t. Wave w: rows [r0+w*16, +16) x all 64 t (4 n-tiles).
// A (W_out) global->reg->bf16; B (h) bf16 in XOR-swizzled LDS [t][k].
__global__ __launch_bounds__(256) void k_out(
    const float* __restrict__ W_out, const float* __restrict__ b_out,
    const float* __restrict__ h_buf, const int* __restrict__ labels,
    float* __restrict__ pm, float* __restrict__ ps, float* __restrict__ ll)
{
    __shared__ __align__(16) unsigned char smem[65536];
    const int tid = threadIdx.x;
    const int r0 = blockIdx.x * 64;
    const int lane = tid & 63, w = tid >> 6;
    const int g = lane >> 4, li = lane & 15;

    // ---- stage h -> bf16 LDS [t][k], byte = (t*1024 + k*2) ^ ((t&7)<<4) ----
    for (int i = 0; i < 32; ++i) {
        int p = tid + i * 256;           // float4 idx over [64][128]
        int t = p >> 7, k4 = p & 127;
        float4 v = ((const float4*)h_buf)[p];
        unsigned p01 = bf16rne(v.x) | (bf16rne(v.y) << 16);
        unsigned p23 = bf16rne(v.z) | (bf16rne(v.w) << 16);
        unsigned byte = (unsigned)(t * 1024 + k4 * 8) ^ ((unsigned)(t & 7) << 4);
        *(uint2*)(smem + byte) = make_uint2(p01, p23);
    }

    f32x4 acc0 = {0.f,0.f,0.f,0.f}, acc1 = {0.f,0.f,0.f,0.f};
    f32x4 acc2 = {0.f,0.f,0.f,0.f}, acc3 = {0.f,0.f,0.f,0.f};
    __syncthreads();

    // ---- A row (clamped for tail block), fragment k = g*8 + j ----
    int rrow = r0 + w * 16 + li;
    int rw = rrow < L_ ? rrow : (L_ - 1);
    const float* ap = W_out + (long)rw * H_ + g * 8;

    #pragma unroll
    for (int kk = 0; kk < 16; ++kk) {
        float4 va = *(const float4*)(ap + kk * 32);
        float4 vb = *(const float4*)(ap + kk * 32 + 4);
        union { unsigned u[4]; bf16x8 v; } A;
        A.u[0] = bf16rne(va.x) | (bf16rne(va.y) << 16);
        A.u[1] = bf16rne(va.z) | (bf16rne(va.w) << 16);
        A.u[2] = bf16rne(vb.x) | (bf16rne(vb.y) << 16);
        A.u[3] = bf16rne(vb.z) | (bf16rne(vb.w) << 16);

        #pragma unroll
        for (int nt = 0; nt < 4; ++nt) {
            int t = nt * 16 + li;
            unsigned byte = (unsigned)(t * 1024 + kk * 64 + g * 16)
                          ^ ((unsigned)(t & 7) << 4);
            bf16x8 B = *(const bf16x8*)(smem + byte);
            f32x4* accp = (nt == 0) ? &acc0 : (nt == 1) ? &acc1
                        : (nt == 2) ? &acc2 : &acc3;
            *accp = __builtin_amdgcn_mfma_f32_16x16x32_bf16(A.v, B, *accp, 0, 0, 0);
        }
    }
    __syncthreads();   // all waves done reading h region

    // ---- logits overlay: lg[64][65] + reduction scratch ----
    float* lg   = (float*)smem;
    float* redb = (float*)(smem + 64 * 65 * 4);
    float* gmax = redb + 256;

    #pragma unroll
    for (int nt = 0; nt < 4; ++nt) {
        const f32x4 a = (nt == 0) ? acc0 : (nt == 1) ? acc1
                      : (nt == 2) ? acc2 : acc3;
        int t = nt * 16 + li;
        #pragma unroll
        for (int q = 0; q < 4; ++q) {
            int rloc = w * 16 + g * 4 + q;
            int r = r0 + rloc;
            float v = -1e30f;
            if (r < L_) v = a[q] + b_out[r];
            lg[rloc * 65 + t] = v;
        }
    }
    __syncthreads();

    const int t = tid & 63, part = tid >> 6;
    float m = -1e30f;
    #pragma unroll
    for (int r16 = 0; r16 < 16; ++r16)
        m = fmaxf(m, lg[(part*16 + r16)*65 + t]);
    redb[part*64 + t] = m;
    __syncthreads();
    if (part == 0)
        gmax[t] = fmaxf(fmaxf(redb[t], redb[64+t]), fmaxf(redb[128+t], redb[192+t]));
    __syncthreads();
    float gm = gmax[t];
    float s = 0.f;
    #pragma unroll
    for (int r16 = 0; r16 < 16; ++r16)
        s += __expf(lg[(part*16 + r16)*65 + t] - gm);
    __syncthreads();
    redb[part*64 + t] = s;
    __syncthreads();
    if (part == 0) {
        pm[t * NBP_ + blockIdx.x] = gm;
        ps[t * NBP_ + blockIdx.x] = redb[t] + redb[64+t] + redb[128+t] + redb[192+t];
        int lb = labels[t];
        if (lb >= r0 && lb < r0 + 64) ll[t] = lg[(lb - r0)*65 + t];
    }
}

// ---------------- K5: combine partials, NLL, total loss ---------------------
__global__ __launch_bounds__(256) void k_final(
    const float* __restrict__ pm, const float* __restrict__ ps,
    const float* __restrict__ ll, const int* __restrict__ labels,
    float* __restrict__ out)
{
    __shared__ float rbuf[8];
    const int t = blockIdx.x, tid = threadIdx.x;
    float m = -1e30f;
    for (int b = tid; b < NB_; b += 256) m = fmaxf(m, pm[t * NBP_ + b]);
    for (int off = 32; off; off >>= 1) m = fmaxf(m, __shfl_down(m, off));
    if ((tid & 63) == 0) rbuf[tid >> 6] = m;
    __syncthreads();
    if (tid == 0) rbuf[4] = fmaxf(fmaxf(rbuf[0], rbuf[1]), fmaxf(rbuf[2], rbuf[3]));
    __syncthreads();
    float M = rbuf[4];
    __syncthreads();
    float s = 0.f;
    for (int b = tid; b < NB_; b += 256)
        s += ps[t * NBP_ + b] * __expf(pm[t * NBP_ + b] - M);
    for (int off = 32; off; off >>= 1) s += __shfl_down(s, off);
    if ((tid & 63) == 0) rbuf[tid >> 6] = s;
    __syncthreads();
    if (tid == 0) {
        float S = rbuf[0] + rbuf[1] + rbuf[2] + rbuf[3];
        int lb = labels[t];
        if (lb != 0) {
            float loss = -(ll[t] - M - __logf(S));
            atomicAdd(out, loss);
        }
    }
}

extern "C" void kernel_launch(void* const* d_in, const int* in_sizes, int n_in,
                              void* d_out, int out_size, void* d_ws, size_t ws_size,
                              hipStream_t stream)
{
    (void)in_sizes; (void)n_in; (void)out_size; (void)ws_size;
    const float* enc    = (const float*)d_in[0];
    const float* h0     = (const float*)d_in[1];
    const float* c0     = (const float*)d_in[2];
    const float* emb    = (const float*)d_in[3];
    const float* W_attn = (const float*)d_in[4];
    const float* b_attn = (const float*)d_in[5];
    const float* W_ih   = (const float*)d_in[6];
    const float* W_hh   = (const float*)d_in[7];
    const float* b_ih   = (const float*)d_in[8];
    const float* b_hh   = (const float*)d_in[9];
    const float* W_out  = (const float*)d_in[10];
    const float* b_out  = (const float*)d_in[11];
    const int* widx     = (const int*)d_in[12];
    const int* labels   = (const int*)d_in[13];
    float* out = (float*)d_out;

    char* ws = (char*)d_ws;
    float* ctx   = (float*)(ws + 0);          // 64*512*4      = 131072
    float* A_pre = (float*)(ws + 131072);     // 64*2048*4     = 524288
    float* h_buf = (float*)(ws + 655360);     // 64*512*4      = 131072
    float* pm    = (float*)(ws + 786688);     // 64*784*4      = 200704
    float* ps    = (float*)(ws + 987392);     // 64*784*4      = 200704
    float* ll    = (float*)(ws + 1188096);    // 64*4

    hipMemsetAsync(h_buf, 0xFF, T_ * H_ * sizeof(float), stream);  // sentinel
    hipMemsetAsync(out, 0, sizeof(float), stream);

    k_attn<<<T_, 256, 0, stream>>>(enc, emb, W_attn, b_attn, widx, ctx);
    k_gatepre<<<256, 256, 0, stream>>>(ctx, W_ih, b_ih, b_hh, A_pre);
    k_lstm<<<NWG_, 256, 0, stream>>>(W_hh, A_pre, h0, c0, h_buf);
    k_out<<<NB_, 256, 0, stream>>>(W_out, b_out, h_buf, labels, pm, ps, ll);
    k_final<<<T_, 256, 0, stream>>>(pm, ps, ll, labels, out);
}

// Round 5
// 237.112 us; speedup vs baseline: 2.1769x; 1.0705x over previous
//
#include <hip/hip_runtime.h>
#include <hip/hip_bf16.h>

#define V_ 100000
#define E_ 256
#define H_ 512
#define L_ 50000
#define S_ 512
#define T_ 64
#define NB_ 782        // ceil(L/64)
#define NBP_ 784
#define NWG_ 32
#define NPF_ 128       // W_out L3-prefetch workgroups fused into k_lstm

typedef short bf16x8 __attribute__((ext_vector_type(8)));
typedef float f32x4 __attribute__((ext_vector_type(4)));

__device__ __forceinline__ float sigm(float x){ return 1.0f/(1.0f+__expf(-x)); }
__device__ __forceinline__ float tanh_fast(float x){
    x = fminf(fmaxf(x, -15.f), 15.f);
    float e = __expf(2.f * x);
    return __fdividef(e - 1.f, e + 1.f);
}
__device__ __forceinline__ unsigned bf16rne(float x){
    unsigned u = __float_as_uint(x);
    return (u + 0x7fffu + ((u >> 16) & 1u)) >> 16;
}
__device__ __forceinline__ float bcast(float v, int l){
    return __uint_as_float(__builtin_amdgcn_readlane(__float_as_uint(v), l));
}

// ---------------- K1: per-step attention (embed -> q -> softmax -> ctx) ----
__global__ __launch_bounds__(256) void k_attn(
    const float* __restrict__ enc, const float* __restrict__ emb,
    const float* __restrict__ W_attn, const float* __restrict__ b_attn,
    const int* __restrict__ word_inputs, float* __restrict__ ctx_out)
{
    __shared__ float e_l[E_];
    __shared__ float q_l[H_];
    __shared__ float sc[S_];
    __shared__ float red[8];
    const int t = blockIdx.x, tid = threadIdx.x;
    const int widx = word_inputs[t];

    e_l[tid] = emb[(long)widx * E_ + tid];
    __syncthreads();

    for (int rr = 0; rr < 2; ++rr) {
        int r = tid + rr * 256;
        const float4* wrow = (const float4*)(W_attn + r * E_);
        const float4* ev = (const float4*)e_l;
        float acc = b_attn[r];
        #pragma unroll 8
        for (int j = 0; j < E_ / 4; ++j) {
            float4 w = wrow[j], e4 = ev[j];
            acc += w.x*e4.x + w.y*e4.y + w.z*e4.z + w.w*e4.w;
        }
        q_l[r] = acc;
    }
    __syncthreads();

    for (int rr = 0; rr < 2; ++rr) {
        int s = tid + rr * 256;
        const float4* er = (const float4*)(enc + s * H_);
        const float4* qv = (const float4*)q_l;
        float acc = 0.f;
        #pragma unroll 8
        for (int j = 0; j < H_ / 4; ++j) {
            float4 a = er[j], b = qv[j];
            acc += a.x*b.x + a.y*b.y + a.z*b.z + a.w*b.w;
        }
        sc[s] = acc;
    }
    __syncthreads();

    float m = fmaxf(sc[tid], sc[tid + 256]);
    for (int off = 32; off; off >>= 1) m = fmaxf(m, __shfl_down(m, off));
    if ((tid & 63) == 0) red[tid >> 6] = m;
    __syncthreads();
    if (tid == 0) red[4] = fmaxf(fmaxf(red[0], red[1]), fmaxf(red[2], red[3]));
    __syncthreads();
    m = red[4];
    float e0 = __expf(sc[tid] - m), e1 = __expf(sc[tid + 256] - m);
    sc[tid] = e0; sc[tid + 256] = e1;
    float ssum = e0 + e1;
    for (int off = 32; off; off >>= 1) ssum += __shfl_down(ssum, off);
    if ((tid & 63) == 0) red[tid >> 6] = ssum;
    __syncthreads();
    if (tid == 0) red[5] = red[0] + red[1] + red[2] + red[3];
    __syncthreads();
    float inv = 1.0f / red[5];

    for (int rr = 0; rr < 2; ++rr) {
        int h = tid + rr * 256;
        float acc = 0.f;
        #pragma unroll 4
        for (int s = 0; s < S_; ++s) acc += sc[s] * enc[s * H_ + h];
        ctx_out[t * H_ + h] = acc * inv;
    }
}

// ---------------- K2: A[t] = W_ih @ ctx_t + b_ih + b_hh ---------------------
__global__ __launch_bounds__(256) void k_gatepre(
    const float* __restrict__ ctx, const float* __restrict__ W_ih,
    const float* __restrict__ b_ih, const float* __restrict__ b_hh,
    float* __restrict__ A_pre)
{
    __shared__ float ctx_t[H_ * 65];   // transposed [k][t], stride 65
    __shared__ float w_l[8 * H_];
    const int tid = threadIdx.x;
    const int r0 = blockIdx.x * 8;

    for (int i = 0; i < 32; ++i) {
        int p = tid + i * 256;
        int t = p >> 7, k4 = p & 127;
        float4 v = ((const float4*)ctx)[p];
        ctx_t[(k4*4+0)*65 + t] = v.x;
        ctx_t[(k4*4+1)*65 + t] = v.y;
        ctx_t[(k4*4+2)*65 + t] = v.z;
        ctx_t[(k4*4+3)*65 + t] = v.w;
    }
    for (int i = 0; i < 4; ++i) {
        int p = tid + i * 256;
        int row = p >> 7, k4 = p & 127;
        float4 v = ((const float4*)W_ih)[(r0 + row) * (H_/4) + k4];
        float* dst = &w_l[row * H_ + k4 * 4];
        dst[0]=v.x; dst[1]=v.y; dst[2]=v.z; dst[3]=v.w;
    }
    __syncthreads();

    const int t = tid & 63, half = tid >> 6;
    const float* w0 = &w_l[(half*2+0) * H_];
    const float* w1 = &w_l[(half*2+1) * H_];
    float acc0 = 0.f, acc1 = 0.f;
    #pragma unroll 4
    for (int k = 0; k < H_; ++k) {
        float cv = ctx_t[k * 65 + t];
        acc0 += w0[k] * cv;
        acc1 += w1[k] * cv;
    }
    int ra = r0 + half * 2, rb = ra + 1;
    A_pre[t * 2048 + ra] = acc0 + b_ih[ra] + b_hh[ra];
    A_pre[t * 2048 + rb] = acc1 + b_ih[rb] + b_hh[rb];
}

// ---------------- K3: persistent LSTM, 8 waves/WG, W reg-resident -----------
// wave = k-slice ks (64 k each); lane = local gate row r = g*16+u.
// blockIdx >= NWG_: L3-prefetch of W_out for k_out (runs on idle CUs).
__global__ __launch_bounds__(512, 2) void k_lstm(
    const float* __restrict__ W_hh, const float* __restrict__ A_pre,
    const float* __restrict__ h0, const float* __restrict__ c0,
    float* __restrict__ h_buf, const float* __restrict__ W_out)
{
    const int tid = threadIdx.x, wg = blockIdx.x;

    if (wg >= NWG_) {
        // ---- W_out L3 warm: stream 102 MB into LLC while LSTM runs ----
        const long total = (long)L_ * H_ / 4;               // float4 count
        const long stride = (long)NPF_ * 512;
        const float4* src = (const float4*)W_out;
        float acc = 0.f;
        for (long i = (long)(wg - NWG_) * 512 + tid; i < total; i += stride) {
            float4 v = src[i];
            acc += v.x + v.y + v.z + v.w;
        }
        asm volatile("" :: "v"(acc));
        return;
    }

    __shared__ float A_l[T_ * 64];      // [t][r]
    __shared__ float red[2][8][64];     // [parity][ks][r]

    const int base = wg * 16;
    const int lane = tid & 63;
    const int ks   = tid >> 6;
    const int G = ((lane >> 4) << 9) + base + (lane & 15);  // global gate row

    // W slice: 64 floats, truly register-resident (low pressure + pin)
    float w[64];
    {
        const float4* wsrc = (const float4*)(W_hh + (long)G * H_ + ks * 64);
        #pragma unroll
        for (int i = 0; i < 16; ++i) {
            float4 v = wsrc[i];
            w[4*i+0]=v.x; w[4*i+1]=v.y; w[4*i+2]=v.z; w[4*i+3]=v.w;
        }
    }
    #pragma unroll
    for (int i = 0; i < 64; ++i) asm volatile("" : "+v"(w[i]));

    // A_pre slice -> LDS (off critical path)
    for (int i = 0; i < 8; ++i) {
        int p = tid + i * 512;          // [0, 4096)
        int tt = p >> 6, rr = p & 63;
        A_l[p] = A_pre[tt * 2048 + ((rr >> 4) << 9) + base + (rr & 15)];
    }
    float c_reg = 0.f;
    if (tid < 16) c_reg = c0[base + tid];
    __syncthreads();

    const unsigned SENT = 0xFFFFFFFFu;

    for (int t = 0; t < T_; ++t) {
        // ---- acquire this wave's 64 h values (1 poll load per lane) ----
        float hv;
        if (t == 0) {
            hv = h0[ks * 64 + lane];
        } else {
            const unsigned* hb = (const unsigned*)h_buf + (t - 1) * H_ + ks * 64;
            unsigned u = __hip_atomic_load(hb + lane, __ATOMIC_RELAXED,
                                           __HIP_MEMORY_SCOPE_AGENT);
            while (u == SENT) {
                __builtin_amdgcn_s_sleep(1);
                u = __hip_atomic_load(hb + lane, __ATOMIC_RELAXED,
                                      __HIP_MEMORY_SCOPE_AGENT);
            }
            hv = __uint_as_float(u);
        }

        // ---- partial dot over this wave's 64-k slice ----
        float a0 = 0.f, a1 = 0.f, a2 = 0.f, a3 = 0.f;
        #pragma unroll
        for (int j = 0; j < 64; j += 4) {
            a0 += bcast(hv, j+0) * w[j+0];
            a1 += bcast(hv, j+1) * w[j+1];
            a2 += bcast(hv, j+2) * w[j+2];
            a3 += bcast(hv, j+3) * w[j+3];
        }
        red[t & 1][ks][lane] = (a0 + a1) + (a2 + a3);
        __syncthreads();

        // ---- wave 0 finalizes: sum 8 partials, gather gates, nonlinearity --
        if (ks == 0) {
            float s = A_l[t * 64 + lane];
            #pragma unroll
            for (int k2 = 0; k2 < 8; ++k2) s += red[t & 1][k2][lane];
            float gf_ = __shfl_down(s, 16);
            float gg_ = __shfl_down(s, 32);
            float go_ = __shfl_down(s, 48);
            if (lane < 16) {
                float gi = sigm(s);
                float gf = sigm(gf_);
                float gg = tanh_fast(gg_);
                float go = sigm(go_);
                float c2 = gf * c_reg + gi * gg;
                c_reg = c2;
                float h2 = go * tanh_fast(c2);
                __hip_atomic_store((unsigned*)h_buf + t * H_ + base + lane,
                                   __float_as_uint(h2),
                                   __ATOMIC_RELAXED, __HIP_MEMORY_SCOPE_AGENT);
            }
        }
        // no trailing barrier: red parity + next-step barrier order reuse
    }
}

// ---------------- K4: MFMA W_out GEMM + per-block softmax partials ----------
__global__ __launch_bounds__(256) void k_out(
    const float* __restrict__ W_out, const float* __restrict__ b_out,
    const float* __restrict__ h_buf, const int* __restrict__ labels,
    float* __restrict__ pm, float* __restrict__ ps, float* __restrict__ ll)
{
    __shared__ __align__(16) unsigned char smem[65536];
    const int tid = threadIdx.x;
    const int r0 = blockIdx.x * 64;
    const int lane = tid & 63, w = tid >> 6;
    const int g = lane >> 4, li = lane & 15;

    // ---- stage h -> bf16 LDS [t][k], byte = (t*1024 + k*2) ^ ((t&7)<<4) ----
    for (int i = 0; i < 32; ++i) {
        int p = tid + i * 256;           // float4 idx over [64][128]
        int t = p >> 7, k4 = p & 127;
        float4 v = ((const float4*)h_buf)[p];
        unsigned p01 = bf16rne(v.x) | (bf16rne(v.y) << 16);
        unsigned p23 = bf16rne(v.z) | (bf16rne(v.w) << 16);
        unsigned byte = (unsigned)(t * 1024 + k4 * 8) ^ ((unsigned)(t & 7) << 4);
        *(uint2*)(smem + byte) = make_uint2(p01, p23);
    }

    f32x4 acc0 = {0.f,0.f,0.f,0.f}, acc1 = {0.f,0.f,0.f,0.f};
    f32x4 acc2 = {0.f,0.f,0.f,0.f}, acc3 = {0.f,0.f,0.f,0.f};
    __syncthreads();

    int rrow = r0 + w * 16 + li;
    int rw = rrow < L_ ? rrow : (L_ - 1);
    const float* ap = W_out + (long)rw * H_ + g * 8;

    #pragma unroll
    for (int kk = 0; kk < 16; ++kk) {
        float4 va = *(const float4*)(ap + kk * 32);
        float4 vb = *(const float4*)(ap + kk * 32 + 4);
        union { unsigned u[4]; bf16x8 v; } A;
        A.u[0] = bf16rne(va.x) | (bf16rne(va.y) << 16);
        A.u[1] = bf16rne(va.z) | (bf16rne(va.w) << 16);
        A.u[2] = bf16rne(vb.x) | (bf16rne(vb.y) << 16);
        A.u[3] = bf16rne(vb.z) | (bf16rne(vb.w) << 16);

        #pragma unroll
        for (int nt = 0; nt < 4; ++nt) {
            int t = nt * 16 + li;
            unsigned byte = (unsigned)(t * 1024 + kk * 64 + g * 16)
                          ^ ((unsigned)(t & 7) << 4);
            bf16x8 B = *(const bf16x8*)(smem + byte);
            f32x4* accp = (nt == 0) ? &acc0 : (nt == 1) ? &acc1
                        : (nt == 2) ? &acc2 : &acc3;
            *accp = __builtin_amdgcn_mfma_f32_16x16x32_bf16(A.v, B, *accp, 0, 0, 0);
        }
    }
    __syncthreads();

    float* lg   = (float*)smem;
    float* redb = (float*)(smem + 64 * 65 * 4);
    float* gmax = redb + 256;

    #pragma unroll
    for (int nt = 0; nt < 4; ++nt) {
        const f32x4 a = (nt == 0) ? acc0 : (nt == 1) ? acc1
                      : (nt == 2) ? acc2 : acc3;
        int t = nt * 16 + li;
        #pragma unroll
        for (int q = 0; q < 4; ++q) {
            int rloc = w * 16 + g * 4 + q;
            int r = r0 + rloc;
            float v = -1e30f;
            if (r < L_) v = a[q] + b_out[r];
            lg[rloc * 65 + t] = v;
        }
    }
    __syncthreads();

    const int t = tid & 63, part = tid >> 6;
    float m = -1e30f;
    #pragma unroll
    for (int r16 = 0; r16 < 16; ++r16)
        m = fmaxf(m, lg[(part*16 + r16)*65 + t]);
    redb[part*64 + t] = m;
    __syncthreads();
    if (part == 0)
        gmax[t] = fmaxf(fmaxf(redb[t], redb[64+t]), fmaxf(redb[128+t], redb[192+t]));
    __syncthreads();
    float gm = gmax[t];
    float s = 0.f;
    #pragma unroll
    for (int r16 = 0; r16 < 16; ++r16)
        s += __expf(lg[(part*16 + r16)*65 + t] - gm);
    __syncthreads();
    redb[part*64 + t] = s;
    __syncthreads();
    if (part == 0) {
        pm[t * NBP_ + blockIdx.x] = gm;
        ps[t * NBP_ + blockIdx.x] = redb[t] + redb[64+t] + redb[128+t] + redb[192+t];
        int lb = labels[t];
        if (lb >= r0 && lb < r0 + 64) ll[t] = lg[(lb - r0)*65 + t];
    }
}

// ---------------- K5: combine partials, NLL, total loss ---------------------
__global__ __launch_bounds__(256) void k_final(
    const float* __restrict__ pm, const float* __restrict__ ps,
    const float* __restrict__ ll, const int* __restrict__ labels,
    float* __restrict__ out)
{
    __shared__ float rbuf[8];
    const int t = blockIdx.x, tid = threadIdx.x;
    float m = -1e30f;
    for (int b = tid; b < NB_; b += 256) m = fmaxf(m, pm[t * NBP_ + b]);
    for (int off = 32; off; off >>= 1) m = fmaxf(m, __shfl_down(m, off));
    if ((tid & 63) == 0) rbuf[tid >> 6] = m;
    __syncthreads();
    if (tid == 0) rbuf[4] = fmaxf(fmaxf(rbuf[0], rbuf[1]), fmaxf(rbuf[2], rbuf[3]));
    __syncthreads();
    float M = rbuf[4];
    __syncthreads();
    float s = 0.f;
    for (int b = tid; b < NB_; b += 256)
        s += ps[t * NBP_ + b] * __expf(pm[t * NBP_ + b] - M);
    for (int off = 32; off; off >>= 1) s += __shfl_down(s, off);
    if ((tid & 63) == 0) rbuf[tid >> 6] = s;
    __syncthreads();
    if (tid == 0) {
        float S = rbuf[0] + rbuf[1] + rbuf[2] + rbuf[3];
        int lb = labels[t];
        if (lb != 0) {
            float loss = -(ll[t] - M - __logf(S));
            atomicAdd(out, loss);
        }
    }
}

extern "C" void kernel_launch(void* const* d_in, const int* in_sizes, int n_in,
                              void* d_out, int out_size, void* d_ws, size_t ws_size,
                              hipStream_t stream)
{
    (void)in_sizes; (void)n_in; (void)out_size; (void)ws_size;
    const float* enc    = (const float*)d_in[0];
    const float* h0     = (const float*)d_in[1];
    const float* c0     = (const float*)d_in[2];
    const float* emb    = (const float*)d_in[3];
    const float* W_attn = (const float*)d_in[4];
    const float* b_attn = (const float*)d_in[5];
    const float* W_ih   = (const float*)d_in[6];
    const float* W_hh   = (const float*)d_in[7];
    const float* b_ih   = (const float*)d_in[8];
    const float* b_hh   = (const float*)d_in[9];
    const float* W_out  = (const float*)d_in[10];
    const float* b_out  = (const float*)d_in[11];
    const int* widx     = (const int*)d_in[12];
    const int* labels   = (const int*)d_in[13];
    float* out = (float*)d_out;

    char* ws = (char*)d_ws;
    float* ctx   = (float*)(ws + 0);          // 64*512*4      = 131072
    float* A_pre = (float*)(ws + 131072);     // 64*2048*4     = 524288
    float* h_buf = (float*)(ws + 655360);     // 64*512*4      = 131072
    float* pm    = (float*)(ws + 786688);     // 64*784*4      = 200704
    float* ps    = (float*)(ws + 987392);     // 64*784*4      = 200704
    float* ll    = (float*)(ws + 1188096);    // 64*4

    hipMemsetAsync(h_buf, 0xFF, T_ * H_ * sizeof(float), stream);  // sentinel
    hipMemsetAsync(out, 0, sizeof(float), stream);

    k_attn<<<T_, 256, 0, stream>>>(enc, emb, W_attn, b_attn, widx, ctx);
    k_gatepre<<<256, 256, 0, stream>>>(ctx, W_ih, b_ih, b_hh, A_pre);
    k_lstm<<<NWG_ + NPF_, 512, 0, stream>>>(W_hh, A_pre, h0, c0, h_buf, W_out);
    k_out<<<NB_, 256, 0, stream>>>(W_out, b_out, h_buf, labels, pm, ps, ll);
    k_final<<<T_, 256, 0, stream>>>(pm, ps, ll, labels, out);
}